// Round 6
// baseline (416.070 us; speedup 1.0000x reference)
//
#include <hip/hip_runtime.h>

typedef __attribute__((ext_vector_type(8))) short short8;
typedef __attribute__((ext_vector_type(4))) float f32x4;
typedef unsigned short u16;
typedef unsigned int u32;

#define FENCE() asm volatile("" ::: "memory")

__device__ __forceinline__ void gld_lds16(const void* g, void* l) {
  __builtin_amdgcn_global_load_lds((const __attribute__((address_space(1))) void*)g,
                                   (__attribute__((address_space(3))) void*)l,
                                   16, 0, 0);
}

__device__ __forceinline__ u16 f2b(float x) {
  union { float f; u32 u; } v; v.f = x;
  u32 u = v.u;
  return (u16)((u + 0x7FFFu + ((u >> 16) & 1u)) >> 16);
}
__device__ __forceinline__ float b2f(u16 x) {
  union { u32 u; float f; } v; v.u = ((u32)x) << 16; return v.f;
}
__device__ __forceinline__ u32 pack_pair(float lo, float hi) {
  return (u32)f2b(lo) | ((u32)f2b(hi) << 16);
}
__device__ __forceinline__ u32 cvtpk(float lo, float hi) {
  u32 r;
  asm("v_cvt_pk_bf16_f32 %0, %1, %2" : "=v"(r) : "v"(lo), "v"(hi));
  return r;
}
__device__ __forceinline__ float fget(const float4& v, int r) {
  switch (r) { case 0: return v.x; case 1: return v.y; case 2: return v.z; default: return v.w; }
}

// ==================== pre-kernel (transpose REMOVED — fused into k_g12) ====================
// blocks [0,768):      Wcomb[kk][j][ci] = sum_co (Wg[co][j]*s1[co]) * Wd[co][ci][kk]
//                      (Wd column + s1 staged to LDS; 8 independent FMA chains)
// block  768:          c0/tWg
// blocks [769,1537):   Wup[kk][co][ci] cast
// blocks [1537,1697):  zero pad frames of outz (5 frames)
__global__ __launch_bounds__(256) void k_pre(const float* __restrict__ Wd, const float* __restrict__ Wg,
                                             const float* __restrict__ Wu,
                                             const float* __restrict__ s1, const float* __restrict__ t1,
                                             const float* __restrict__ bg,
                                             u16* __restrict__ outz,
                                             u16* __restrict__ Wup, u16* __restrict__ Wcomb,
                                             float* __restrict__ c0, float* __restrict__ tWg) {
  __shared__ float wdv[256];
  __shared__ float ws1[256];
  int blk = blockIdx.x;
  int tid = threadIdx.x;
  if (blk < 768) {  // Wcomb
    int kk = blk >> 8;
    int ci = blk & 255;
    int j = tid;
    wdv[tid] = b2f(f2b(Wd[(u32)tid * 768 + (u32)ci * 3 + kk]));
    ws1[tid] = s1[tid];
    __syncthreads();
    float a[8] = {0.f, 0.f, 0.f, 0.f, 0.f, 0.f, 0.f, 0.f};
    for (int co = 0; co < 256; co += 8) {
#pragma unroll
      for (int u = 0; u < 8; ++u)
        a[u] = fmaf(b2f(f2b(Wg[(co + u) * 256 + j] * ws1[co + u])), wdv[co + u], a[u]);
    }
    float s = ((a[0] + a[1]) + (a[2] + a[3])) + ((a[4] + a[5]) + (a[6] + a[7]));
    Wcomb[(size_t)kk * 65536 + (size_t)j * 256 + ci] = f2b(s);
    return;
  }
  if (blk == 768) {  // c0[j] = t1 @ Wg[:,j] + bg[j]
    int j = tid;
    float a0 = 0.f, a1 = 0.f, a2 = 0.f, a3 = 0.f;
    for (int co = 0; co < 256; co += 4) {
      a0 = fmaf(t1[co + 0], Wg[(co + 0) * 256 + j], a0);
      a1 = fmaf(t1[co + 1], Wg[(co + 1) * 256 + j], a1);
      a2 = fmaf(t1[co + 2], Wg[(co + 2) * 256 + j], a2);
      a3 = fmaf(t1[co + 3], Wg[(co + 3) * 256 + j], a3);
    }
    float a = (a0 + a1) + (a2 + a3);
    tWg[j] = a;
    c0[j] = a + bg[j];
    return;
  }
  if (blk < 1537) {  // Wup cast
    int id = (blk - 769) * 256 + tid;
    int kk = id >> 16;
    int rem = id & 65535;
    int a = rem >> 8, b = rem & 255;
    Wup[id] = f2b(Wu[(u32)a * 768 + (u32)b * 3 + kk]);
    return;
  }
  // zero pad frames of outz (frames f*129, f=0..4)
  int gid = (blk - 1537) * 256 + tid;
  int i = gid * 8;
  int f = i >> 16;
  int off = i & 65535;
  u16* dst = outz + (size_t)f * 129 * 65536 + off;
  *(uint4*)dst = make_uint4(0u, 0u, 0u, 0u);
}

// ---------------- output store helpers ----------------
__device__ __forceinline__ void store_pairs(u16* base, int row0, int stride, int colb,
                                            const float v[4], bool ev) {
  float pv[4];
#pragma unroll
  for (int r = 0; r < 4; ++r) pv[r] = __shfl_xor(v[r], 1, 64);
  u32 wd0 = ev ? pack_pair(v[0], pv[0]) : pack_pair(pv[0], v[0]);
  u32 wd1 = ev ? pack_pair(v[1], pv[1]) : pack_pair(pv[1], v[1]);
  u32 wd2 = ev ? pack_pair(v[2], pv[2]) : pack_pair(pv[2], v[2]);
  u32 wd3 = ev ? pack_pair(v[3], pv[3]) : pack_pair(pv[3], v[3]);
  u32 wa = ev ? wd0 : wd2;
  u32 wb = ev ? wd1 : wd3;
  int rs = ev ? 0 : 2;
  *(u32*)(base + (size_t)(row0 + rs) * stride + colb) = wa;
  *(u32*)(base + (size_t)(row0 + rs + 1) * stride + colb) = wb;
}

__device__ __forceinline__ void store_pairs_f32(float* base, int row0, int stride, int colb,
                                                const float v[4], bool ev) {
  float pv[4];
#pragma unroll
  for (int r = 0; r < 4; ++r) pv[r] = __shfl_xor(v[r], 1, 64);
  float2 wa, wb;
  if (ev) { wa = make_float2(v[0], pv[0]); wb = make_float2(v[1], pv[1]); }
  else    { wa = make_float2(pv[2], v[2]); wb = make_float2(pv[3], v[3]); }
  int rs = ev ? 0 : 2;
  *(float2*)(base + (size_t)(row0 + rs) * stride + colb) = wa;
  *(float2*)(base + (size_t)(row0 + rs + 1) * stride + colb) = wb;
}

// ================= 256x256 8-phase GEMM core (used by k_g3; round-1 verified) =================
__device__ __forceinline__ void stage_part(int s, const u16* Ab, const u16* Bb,
                                           u16* sA, u16* sB, int wuni, int g0) {
  if (s >= 48) return;
  const int tau = s >> 2;
  const int pt = s & 3;              // 0=B0,1=B1,2=A0,3=A1
  const int toff = ((tau >> 2) << 16) + ((tau & 3) << 6);
  const int half = pt & 1;
  const u16* src = ((pt & 2) ? Ab : Bb) + toff + (half << 15) + g0;
  u16* dst = ((pt & 2) ? sA : sB) + ((tau & 1) << 14) + (half << 13) + wuni;
  gld_lds16(src, dst);
  gld_lds16(src + 16384, dst + 4096);
}

template<int QUAD, int NH>
__device__ __forceinline__ void mfma_quad(f32x4 (&acc)[8][4], const short8 (&af)[2][4],
                                          const short8 (&bf)[2][2][2]) {
#pragma unroll
  for (int k = 0; k < 2; ++k)
#pragma unroll
    for (int m = 0; m < 4; ++m)
#pragma unroll
      for (int nj = 0; nj < 2; ++nj)
        acc[QUAD * 4 + m][NH * 2 + nj] = __builtin_amdgcn_mfma_f32_16x16x32_bf16(
            af[k][m], bf[NH][k][nj], acc[QUAD * 4 + m][NH * 2 + nj], 0, 0, 0);
}

__device__ __forceinline__ void gemm256_core(const u16* __restrict__ Ab, const u16* __restrict__ Bb,
                                             u16* sA, u16* sB, int tid, f32x4 (&acc)[8][4]) {
  const int lane = tid & 63;
  const int w = tid >> 6;
  const int wr = w >> 2;
  const int wc = w & 3;
  const int m16 = lane & 15;
  const int xorm = (lane & 7) << 4;
  const int q16b = (lane >> 4) << 4;
  const int koffe0 = ((q16b) ^ xorm) >> 1;
  const int koffe1 = ((64 + q16b) ^ xorm) >> 1;
  const int srow = tid >> 3;
  const int scol = ((tid & 7) ^ (srow & 7)) << 3;
  const int g0 = srow * 256 + scol;
  const int wuni = w << 9;

#pragma unroll
  for (int i = 0; i < 8; ++i)
#pragma unroll
    for (int j = 0; j < 4; ++j) acc[i][j] = (f32x4){0.f, 0.f, 0.f, 0.f};

#pragma unroll
  for (int s = 0; s < 7; ++s) stage_part(s, Ab, Bb, sA, sB, wuni, g0);
  asm volatile("s_waitcnt vmcnt(6)" ::: "memory");
  __builtin_amdgcn_s_barrier();
  FENCE();

  short8 af[2][4];
  short8 bf[2][2][2];
#pragma unroll 2
  for (int kt = 0; kt < 12; ++kt) {
    const int cb = kt & 1;
    const u16* aH = sA + cb * 16384 + wr * 8192;
    const u16* bH = sB + cb * 16384 + (wc >> 1) * 8192;
    const int bR0 = (wc & 1) << 6;
#pragma unroll
    for (int m = 0; m < 4; ++m) {
      const u16* p = aH + (m * 16 + m16) * 64;
      af[0][m] = *(const short8*)(p + koffe0);
      af[1][m] = *(const short8*)(p + koffe1);
    }
#pragma unroll
    for (int nh = 0; nh < 2; ++nh)
#pragma unroll
      for (int nj = 0; nj < 2; ++nj) {
        const u16* p = bH + (bR0 + (nh * 2 + nj) * 16 + m16) * 64;
        bf[nh][0][nj] = *(const short8*)(p + koffe0);
        bf[nh][1][nj] = *(const short8*)(p + koffe1);
      }
    stage_part(4 * kt + 7, Ab, Bb, sA, sB, wuni, g0);
    FENCE();
    __builtin_amdgcn_s_barrier();
    FENCE();
    __builtin_amdgcn_s_setprio(1);
    mfma_quad<0, 0>(acc, af, bf);
    __builtin_amdgcn_s_setprio(0);
    FENCE();
    __builtin_amdgcn_s_barrier();
    FENCE();
    stage_part(4 * kt + 8, Ab, Bb, sA, sB, wuni, g0);
    FENCE();
    __builtin_amdgcn_s_barrier();
    FENCE();
    __builtin_amdgcn_s_setprio(1);
    mfma_quad<0, 1>(acc, af, bf);
    __builtin_amdgcn_s_setprio(0);
    FENCE();
    __builtin_amdgcn_s_barrier();
    FENCE();
#pragma unroll
    for (int m = 0; m < 4; ++m) {
      const u16* p = aH + (64 + m * 16 + m16) * 64;
      af[0][m] = *(const short8*)(p + koffe0);
      af[1][m] = *(const short8*)(p + koffe1);
    }
    stage_part(4 * kt + 9, Ab, Bb, sA, sB, wuni, g0);
    FENCE();
    __builtin_amdgcn_s_barrier();
    FENCE();
    __builtin_amdgcn_s_setprio(1);
    mfma_quad<1, 0>(acc, af, bf);
    __builtin_amdgcn_s_setprio(0);
    FENCE();
    __builtin_amdgcn_s_barrier();
    FENCE();
    stage_part(4 * kt + 10, Ab, Bb, sA, sB, wuni, g0);
    FENCE();
    __builtin_amdgcn_s_barrier();
    FENCE();
    __builtin_amdgcn_s_setprio(1);
    mfma_quad<1, 1>(acc, af, bf);
    __builtin_amdgcn_s_setprio(0);
    if (kt < 10) asm volatile("s_waitcnt vmcnt(6)" ::: "memory");
    else         asm volatile("s_waitcnt vmcnt(0)" ::: "memory");
    __builtin_amdgcn_s_barrier();
    FENCE();
  }
}

// ================= fused G12: A staged directly from fp32 x (transpose-in-staging) =========
// A logical: [256 p][64 ci] per K-tile; LDS phys: byte = row*128 + (col ^ (f(row)<<4)),
// f(row) = ((row>>2)&3) ^ ((row&3)<<1) ^ (((row>>4)&1)<<2)  — 2-way (free) on BOTH the
// stride-4-row write pattern and the consecutive-row read pattern (enumerated).
// Counted-vmcnt (FIFO): per kt issue order [ph1: B0(kt+2)x2][ph2: B1(kt+2)x2 + A(kt+2)x8];
// ph2 wait vmcnt(2) drains A(kt+1)+B(kt+1) (2 newest = always ph1's B0(kt+2)). kt>=10: vmcnt(0).
__global__ __launch_bounds__(512) void k_g12(const float* __restrict__ x, const u16* __restrict__ Wcomb,
                                             const float* __restrict__ c0, const float* __restrict__ tWg,
                                             u16* __restrict__ outz, float* __restrict__ edge) {
  __shared__ u16 sA[32768];
  __shared__ u16 sB[32768];
  int bsw = (int)blockIdx.x;
  int bt = (bsw & 7) * 64 + (bsw >> 3);   // XCD swizzle (512 = 8*64)
  int b = bt >> 7, t = bt & 127;
  int tid = threadIdx.x;
  const int lane = tid & 63;
  const int w = tid >> 6;
  const int wr = w >> 2, wc = w & 3;
  const int m16 = lane & 15;
  const int xorm = (lane & 7) << 4;              // B swizzle (old)
  const int q16b = (lane >> 4) << 4;
  const int koffe0 = (q16b ^ xorm) >> 1;
  const int koffe1 = ((64 + q16b) ^ xorm) >> 1;
  const int gAx = (((lane >> 2) & 3) ^ ((lane & 3) << 1)) << 4;   // A swizzle lane part
  const int kA00 = (q16b ^ gAx) >> 1;            // half0, m even
  const int kA01 = ((q16b ^ gAx) ^ 64) >> 1;     // half0, m odd
  const int kA10 = (((64 | q16b) ^ gAx)) >> 1;   // half1, m even
  const int kA11 = (((64 | q16b) ^ gAx) ^ 64) >> 1;  // half1, m odd
  const int srow = tid >> 3;
  const int scol = ((tid & 7) ^ (srow & 7)) << 3;
  const int g0 = srow * 256 + scol;
  const int wuni = w << 9;
  const int o = w, q = lane;
  const int qpart = (q & 3) ^ (((q >> 2) & 1) << 2);

  float4 rf[8];

  auto issueA = [&](int tau) {
    int fr = tau >> 2, c = tau & 3;
    int ft = t - 1 + fr;
    int ftc = ft < 0 ? 0 : (ft > 127 ? 127 : ft);
    const float* xb = x + ((size_t)(b * 128 + ftc)) * 65536 + (size_t)(c * 64 + o * 8) * 256 + (q << 2);
#pragma unroll
    for (int k = 0; k < 8; ++k) rf[k] = *(const float4*)(xb + k * 256);
  };
  auto cvtwrA = [&](int tau) {
    int ft = t - 1 + (tau >> 2);
    u32 msk = (ft >= 0 && ft <= 127) ? 0xFFFFFFFFu : 0u;
    u16* sAd = sA + ((tau & 1) << 14);
#pragma unroll
    for (int r = 0; r < 4; ++r) {
      u32 w0 = cvtpk(fget(rf[0], r), fget(rf[1], r)) & msk;
      u32 w1 = cvtpk(fget(rf[2], r), fget(rf[3], r)) & msk;
      u32 w2 = cvtpk(fget(rf[4], r), fget(rf[5], r)) & msk;
      u32 w3 = cvtpk(fget(rf[6], r), fget(rf[7], r)) & msk;
      *(uint4*)(sAd + (4 * q + r) * 64 + ((o ^ qpart ^ (r << 1)) << 3)) = make_uint4(w0, w1, w2, w3);
    }
  };
  auto stageB = [&](int tau, int half) {
    const int toff = ((tau >> 2) << 16) + ((tau & 3) << 6);
    const u16* src = Wcomb + toff + (half << 15) + g0;
    u16* dst = sB + ((tau & 1) << 14) + (half << 13) + wuni;
    gld_lds16(src, dst);
    gld_lds16(src + 16384, dst + 4096);
  };

  f32x4 acc[8][4];
#pragma unroll
  for (int i = 0; i < 8; ++i)
#pragma unroll
    for (int j = 0; j < 4; ++j) acc[i][j] = (f32x4){0.f, 0.f, 0.f, 0.f};

  // ---- prologue ----
  issueA(0);
  asm volatile("s_waitcnt vmcnt(0)" ::: "memory");
  cvtwrA(0);
  stageB(0, 0); stageB(0, 1);
  __builtin_amdgcn_sched_barrier(0);
  stageB(1, 0); stageB(1, 1);
  __builtin_amdgcn_sched_barrier(0);
  issueA(1);
  __builtin_amdgcn_sched_barrier(0);
  asm volatile("s_waitcnt vmcnt(12)" ::: "memory");  // drains B(0)
  asm volatile("s_waitcnt lgkmcnt(0)" ::: "memory"); // publish sA[0] writes
  __builtin_amdgcn_s_barrier();
  FENCE();

  short8 af[2][4];
  short8 bf[2][2][2];
#pragma unroll 2
  for (int kt = 0; kt < 12; ++kt) {
    const int cb = kt & 1;
    const u16* aH = sA + cb * 16384 + wr * 8192;
    const u16* bH = sB + cb * 16384 + (wc >> 1) * 8192;
    const int bR0 = (wc & 1) << 6;
    // ---- phase 0: ds_read A-quad0 + all B; bar; MFMA Q00; bar ----
#pragma unroll
    for (int m = 0; m < 4; ++m) {
      const u16* p = aH + (m * 16 + m16) * 64;
      af[0][m] = *(const short8*)(p + ((m & 1) ? kA01 : kA00));
      af[1][m] = *(const short8*)(p + ((m & 1) ? kA11 : kA10));
    }
#pragma unroll
    for (int nh = 0; nh < 2; ++nh)
#pragma unroll
      for (int nj = 0; nj < 2; ++nj) {
        const u16* p = bH + (bR0 + (nh * 2 + nj) * 16 + m16) * 64;
        bf[nh][0][nj] = *(const short8*)(p + koffe0);
        bf[nh][1][nj] = *(const short8*)(p + koffe1);
      }
    FENCE();
    __builtin_amdgcn_s_barrier();
    FENCE();
    __builtin_amdgcn_s_setprio(1);
    mfma_quad<0, 0>(acc, af, bf);
    __builtin_amdgcn_s_setprio(0);
    FENCE();
    __builtin_amdgcn_s_barrier();
    FENCE();
    // ---- phase 1: stage B0(kt+2); bar; MFMA Q01; bar ----
    if (kt < 10) stageB(kt + 2, 0);
    FENCE();
    __builtin_amdgcn_s_barrier();
    FENCE();
    __builtin_amdgcn_s_setprio(1);
    mfma_quad<0, 1>(acc, af, bf);
    __builtin_amdgcn_s_setprio(0);
    FENCE();
    __builtin_amdgcn_s_barrier();
    FENCE();
    // ---- phase 2: ds_read A-quad1; vmcnt; convert+write A(kt+1); stage B1(kt+2); issue A(kt+2);
    //              bar; MFMA Q10; bar ----
#pragma unroll
    for (int m = 0; m < 4; ++m) {
      const u16* p = aH + (64 + m * 16 + m16) * 64;
      af[0][m] = *(const short8*)(p + ((m & 1) ? kA01 : kA00));
      af[1][m] = *(const short8*)(p + ((m & 1) ? kA11 : kA10));
    }
    if (kt < 10)       asm volatile("s_waitcnt vmcnt(2)" ::: "memory");
    else if (kt == 10) asm volatile("s_waitcnt vmcnt(0)" ::: "memory");
    if (kt < 11) cvtwrA(kt + 1);
    if (kt < 10) {
      stageB(kt + 2, 1);
      __builtin_amdgcn_sched_barrier(0);
      issueA(kt + 2);
    }
    FENCE();
    __builtin_amdgcn_s_barrier();
    FENCE();
    __builtin_amdgcn_s_setprio(1);
    mfma_quad<1, 0>(acc, af, bf);
    __builtin_amdgcn_s_setprio(0);
    FENCE();
    __builtin_amdgcn_s_barrier();
    FENCE();
    // ---- phase 3: MFMA Q11; publish LDS writes; bar ----
    __builtin_amdgcn_s_setprio(1);
    mfma_quad<1, 1>(acc, af, bf);
    __builtin_amdgcn_s_setprio(0);
    asm volatile("s_waitcnt lgkmcnt(0)" ::: "memory");
    __builtin_amdgcn_s_barrier();
    FENCE();
  }

  int qf = lane >> 4, cc16 = lane & 15;
  bool ev = (lane & 1) == 0;
  float c0v[4], tWgv[4];
#pragma unroll
  for (int ni = 0; ni < 4; ++ni) {
    int j = wc * 64 + ni * 16 + cc16;
    c0v[ni] = c0[j];
    tWgv[ni] = tWg[j];
  }
  u16* obase = outz + (size_t)(b * 129 + t + 1) * 65536;
#pragma unroll
  for (int mi = 0; mi < 8; ++mi) {
    int row0 = wr * 128 + mi * 16 + qf * 4;
#pragma unroll
    for (int ni = 0; ni < 4; ++ni) {
      float v[4];
#pragma unroll
      for (int r = 0; r < 4; ++r) v[r] = acc[mi][ni][r] + c0v[ni];
      store_pairs(obase, row0, 256, wc * 64 + ni * 16 + (cc16 & ~1), v, ev);
    }
  }
  if (wr == 0 && qf == 0) {
    float* eb = edge + (size_t)bt * 1024;
#pragma unroll
    for (int ni = 0; ni < 4; ++ni) {
      float vE[4];
#pragma unroll
      for (int r = 0; r < 4; ++r) vE[r] = acc[0][ni][r] + tWgv[ni];
      store_pairs_f32(eb, 0, 256, wc * 64 + ni * 16 + (cc16 & ~1), vE, ev);
    }
  }
}

// ---- fixup: overwrite p<4 nodes with GCN aggregation (closed-form dinv) ----
__device__ __forceinline__ float dinv0(int t) {
  if (t == 0) return 0.44721359549995793f;   // 1/sqrt(5)
  if (t == 127) return 0.7071067811865476f;  // 1/sqrt(2)
  return 0.4082482904638631f;                // 1/sqrt(6)
}
__global__ __launch_bounds__(256) void k_fix(const float* __restrict__ edge, const float* __restrict__ bg,
                                             u16* __restrict__ outz) {
  int bt = blockIdx.x;
  int b = bt >> 7;
  int t = bt & 127;
  int j = threadIdx.x;
  const float ISQ2 = 0.7071067811865476f;
  float bgv = bg[j];
  float e_t = edge[(size_t)bt * 1024 + j];
  float At = dinv0(t);
  float o0 = bgv + At * At * e_t;
  if (t <= 126) {
    float At1 = dinv0(t + 1);
    const float* en = edge + (size_t)(bt + 1) * 1024;
    float s = At1 * en[j] + ISQ2 * (en[256 + j] + en[512 + j] + en[768 + j]);
    o0 += At * s;
  }
  float em1 = 0.f, Atm1 = 0.f;
  if (t >= 1) {
    Atm1 = dinv0(t - 1);
    em1 = edge[(size_t)(bt - 1) * 1024 + j];
    o0 += At * Atm1 * em1;
  }
  u16* ob = outz + (size_t)(b * 129 + t + 1) * 65536;
  ob[j] = f2b(o0);
#pragma unroll
  for (int k = 1; k <= 3; ++k) {
    float m = edge[(size_t)bt * 1024 + k * 256 + j];
    float ok = (t == 0) ? (bgv + m) : (bgv + 0.5f * m + ISQ2 * Atm1 * em1);
    ob[k * 256 + j] = f2b(ok);
  }
}

// ---- G3: y[bt][co][p] = (Wup_kk @ outz_frames^T)*s2 + t2, fp32 out ----
__global__ __launch_bounds__(512, 2) void k_g3(const u16* __restrict__ outz, const u16* __restrict__ Wup,
                                               const float* __restrict__ s2, const float* __restrict__ t2,
                                               float* __restrict__ y) {
  __shared__ u16 sA[32768];
  __shared__ u16 sB[32768];
  int bsw = (int)blockIdx.x;
  int bt = (bsw & 7) * 64 + (bsw >> 3);
  int b = bt >> 7, t = bt & 127;
  int tid = threadIdx.x;
  const u16* Ab = Wup;
  const u16* Bb = outz + (size_t)(b * 129 + t) * 65536;
  f32x4 acc[8][4];
  gemm256_core(Ab, Bb, sA, sB, tid, acc);

  int lane = tid & 63, w = tid >> 6, wr = w >> 2, wc = w & 3;
  int q = lane >> 4, cc16 = lane & 15;
  bool ev = (lane & 1) == 0;
  float* ybase = y + (size_t)bt * 65536;
#pragma unroll
  for (int mi = 0; mi < 8; ++mi) {
    int rl = wr * 128 + mi * 16 + q * 4;
    float4 s4 = *(const float4*)(s2 + rl);
    float4 t4 = *(const float4*)(t2 + rl);
#pragma unroll
    for (int ni = 0; ni < 4; ++ni) {
      float v[4];
      v[0] = acc[mi][ni][0] * s4.x + t4.x;
      v[1] = acc[mi][ni][1] * s4.y + t4.y;
      v[2] = acc[mi][ni][2] * s4.z + t4.z;
      v[3] = acc[mi][ni][3] * s4.w + t4.w;
      store_pairs_f32(ybase, rl, 256, wc * 64 + ni * 16 + (cc16 & ~1), v, ev);
    }
  }
}

extern "C" void kernel_launch(void* const* d_in, const int* in_sizes, int n_in,
                              void* d_out, int out_size, void* d_ws, size_t ws_size,
                              hipStream_t stream) {
  (void)in_sizes; (void)n_in; (void)out_size; (void)ws_size;
  const float* x  = (const float*)d_in[0];
  const float* Wd = (const float*)d_in[2];
  const float* s1 = (const float*)d_in[3];
  const float* t1 = (const float*)d_in[4];
  const float* Wg = (const float*)d_in[5];
  const float* bg = (const float*)d_in[6];
  const float* Wu = (const float*)d_in[7];
  const float* s2 = (const float*)d_in[8];
  const float* t2 = (const float*)d_in[9];
  float* y = (float*)d_out;
  char* ws = (char*)d_ws;
  // outz: 517 frames (4*129+1), frames b*129 are shared zero pads. xTz is GONE (fused).
  u16*   outz  = (u16*)(ws);                    // 67,764,224 B
  u16*   Wup   = (u16*)(ws + 67764224);         // 384 KiB
  u16*   Wcomb = (u16*)(ws + 68157440);         // 384 KiB
  float* c0    = (float*)(ws + 68550656);       // 1 KiB
  float* tWg   = (float*)(ws + 68551680);       // 1 KiB
  float* edge  = (float*)d_out;                 // scratch in d_out, overwritten by k_g3

  k_pre<<<dim3(1697), dim3(256), 0, stream>>>(Wd, Wg, Wu, s1, t1, bg, outz, Wup, Wcomb, c0, tWg);
  k_g12<<<dim3(512), dim3(512), 0, stream>>>(x, Wcomb, c0, tWg, outz, edge);
  k_fix<<<dim3(512), dim3(256), 0, stream>>>(edge, bg, outz);
  k_g3<<<dim3(512), dim3(512), 0, stream>>>(outz, Wup, s2, t2, y);
}